// Round 4
// baseline (20.652 us; speedup 1.0000x reference)
//
#include <hip/hip_runtime.h>

// Fused quanvolution + FC + log_softmax via MFMA (gfx950), pixel-order K.
//
// logits[16][10] = q[16][784] @ w'[784][10] with mfma_f32_16x16x32_bf16,
// where K is indexed by RAW PIXEL order (any consistent K-permutation of
// A and B cancels). A frag = 8 contiguous pixels (one aligned 32B run,
// 2 contiguous dwordx4). B frag = fc_w gathered via qidx once in prologue.
// 4-way K-split over waves (kb = wv + 4I, 25 kblocks of 32), partials
// combined via 3KB LDS. C frag (m89): col=lane&15, row=(lane>>4)*4+reg.

typedef __attribute__((ext_vector_type(8))) short short8;
typedef __attribute__((ext_vector_type(4))) float f32x4;

constexpr int WAVES = 4;
constexpr int BLOCK = WAVES * 64;
constexpr int IMGS  = 16;
constexpr int NITER = 7;

static __device__ __forceinline__ short f2bf(float f) {
    union { float f; unsigned u; } v; v.f = f;
    unsigned r = v.u + 0x7fffu + ((v.u >> 16) & 1u);   // round-to-nearest-even
    return (short)(r >> 16);
}

__global__ __launch_bounds__(BLOCK, 4)
void quanv_mfma(const float* __restrict__ x,
                const float* __restrict__ vqc,
                const float* __restrict__ fc_w,
                const float* __restrict__ fc_b,
                const float* __restrict__ bias,
                float* __restrict__ out,
                int B)
{
    __shared__ float cpart[3][64 * 4];

    const int tid  = threadIdx.x;
    const int lane = tid & 63;
    const int wv   = tid >> 6;
    const int i16  = lane & 15;          // image (A row) / class (B col)
    const int g    = lane >> 4;          // k-subgroup

    const int imgBase = blockIdx.x * IMGS;
    const int imgLane = imgBase + i16;
    const long xb = (long)(imgLane < B ? imgLane : B - 1) * 784;
    const int  k0 = wv * 32 + 8 * g;     // pixel offset at I=0; +128 per iter

    const float* __restrict__ xp = x + xb + k0;

    // ---- x prefetch for I=0,1 first (starts the HBM stream immediately) ----
    float4 bufA[2], bufB[2];
    bufA[0] = *reinterpret_cast<const float4*>(xp);
    bufB[0] = *reinterpret_cast<const float4*>(xp + 4);
    bufA[1] = *reinterpret_cast<const float4*>(xp + 128);
    bufB[1] = *reinterpret_cast<const float4*>(xp + 132);

    // ---- circuit params ----
    float S0, C0, S1, C1, S2, C2, S3, C3;
    __sincosf(vqc[0], &S0, &C0);
    __sincosf(vqc[1], &S1, &C1);
    __sincosf(vqc[2], &S2, &C2);
    __sincosf(vqc[3], &S3, &C3);

    // ---- gather B fragments: w'[cls][pix] = fc_w[cls][qidx(pix)] ----
    // pair (pix even): za,zb weights are ADJACENT in q-space -> float2 loads
    const int ncl = (i16 < 10) ? i16 : 9;
    const float* __restrict__ wrow = fc_w + ncl * 784;
    short8 bf[NITER];
    #pragma unroll
    for (int I = 0; I < NITER; ++I) {
        short8 t;
        #pragma unroll
        for (int u = 0; u < 4; ++u) {
            int pix = k0 + 128 * I + 2 * u;
            pix = pix < 782 ? pix : 782;            // clamp (tail lanes masked)
            const int y  = pix / 28;
            const int c  = pix - 28 * y;
            const int qp = ((y >> 1) * 14 + (c >> 1)) * 4 + (y & 1) * 2;
            const float2 w2 = *reinterpret_cast<const float2*>(wrow + qp);
            t[2 * u]     = f2bf(w2.x);
            t[2 * u + 1] = f2bf(w2.y);
        }
        bf[I] = t;
    }

    f32x4 acc = {0.f, 0.f, 0.f, 0.f};
    int rr = k0 % 28;            // pixel-in-row remainder (row length 28)
    int pi = (k0 / 28) & 1;      // row parity -> param-set select

    #pragma unroll
    for (int I = 0; I < NITER; ++I) {
        const float4 a4 = bufA[I & 1];
        const float4 b4 = bufB[I & 1];

        // 2-deep prefetch (conditions fold at compile time under unroll)
        if (I + 2 <= NITER - 2) {                    // plain: k+7 <= 767
            bufA[I & 1] = *reinterpret_cast<const float4*>(xp + 128 * (I + 2));
            bufB[I & 1] = *reinterpret_cast<const float4*>(xp + 128 * (I + 2) + 4);
        } else if (I + 2 == NITER - 1) {             // last tile: clamp to 776
            const int kl = (k0 + 128 * (NITER - 1) <= 776) ? 128 * (NITER - 1)
                                                           : 776 - k0;
            bufA[I & 1] = *reinterpret_cast<const float4*>(xp + kl);
            bufB[I & 1] = *reinterpret_cast<const float4*>(xp + kl + 4);
        }

        float q[8];
        #pragma unroll
        for (int u = 0; u < 4; ++u) {
            const float xa = (u == 0) ? a4.x : (u == 1) ? a4.z
                           : (u == 2) ? b4.x : b4.z;
            const float xv = (u == 0) ? a4.y : (u == 1) ? a4.w
                           : (u == 2) ? b4.y : b4.w;
            const int   pu = pi ^ ((rr + 2 * u) >= 28);   // row parity of pair
            const float CA = pu ? C2 : C0, SA = pu ? S2 : S0;
            const float CB = pu ? C3 : C1, SB = pu ? S3 : S1;
            float sa, ca, sb, cb;
            __sincosf(xa, &sa, &ca);
            __sincosf(xv, &sb, &cb);
            float za = CA * ca + SA * (sa * sb);
            float zb = CB * (ca * cb) + SB * sb;
            if (I == NITER - 1) {                    // only last tile masks
                const float m = (k0 + 128 * I + 2 * u) < 784 ? 1.f : 0.f;
                za *= m; zb *= m;
            }
            q[2 * u]     = za;
            q[2 * u + 1] = zb;
        }
        rr += 16;
        if (rr >= 28) { rr -= 28; pi ^= 1; }         // predicated, no branch

        short8 a;
        #pragma unroll
        for (int e = 0; e < 8; ++e) a[e] = f2bf(q[e]);

        acc = __builtin_amdgcn_mfma_f32_16x16x32_bf16(a, bf[I], acc, 0, 0, 0);
    }

    // ---- K-split combine through LDS ----
    if (wv > 0)
        *reinterpret_cast<f32x4*>(&cpart[wv - 1][lane * 4]) = acc;
    __syncthreads();

    if (wv == 0) {
        #pragma unroll
        for (int p = 0; p < 3; ++p)
            acc += *reinterpret_cast<const f32x4*>(&cpart[p][lane * 4]);
        const float bk = (i16 < 10) ? (fc_b[i16] - bias[i16]) : 0.f;

        #pragma unroll
        for (int r = 0; r < 4; ++r) {
            const float lg = acc[r] + bk;
            float mx = (i16 < 10) ? lg : -3.0e38f;
            #pragma unroll
            for (int off = 1; off < 16; off <<= 1)
                mx = fmaxf(mx, __shfl_xor(mx, off, 64));
            float s = (i16 < 10) ? __expf(lg - mx) : 0.f;
            #pragma unroll
            for (int off = 1; off < 16; off <<= 1)
                s += __shfl_xor(s, off, 64);
            const int im = imgBase + g * 4 + r;      // C row = g*4 + reg [m89]
            if (i16 < 10 && im < B)
                out[(long)im * 10 + i16] = lg - mx - __logf(s);
        }
    }
}

extern "C" void kernel_launch(void* const* d_in, const int* in_sizes, int n_in,
                              void* d_out, int out_size, void* d_ws, size_t ws_size,
                              hipStream_t stream) {
    const float* x    = (const float*)d_in[0];
    const float* vqc  = (const float*)d_in[1];
    const float* fc_w = (const float*)d_in[2];
    const float* fc_b = (const float*)d_in[3];
    const float* bias = (const float*)d_in[4];
    float* outp = (float*)d_out;

    const int B = in_sizes[0] / 784;
    const int nblocks = (B + IMGS - 1) / IMGS;
    hipLaunchKernelGGL(quanv_mfma, dim3(nblocks), dim3(BLOCK), 0, stream,
                       x, vqc, fc_w, fc_b, bias, outp, B);
}

// Round 5
// 17.203 us; speedup vs baseline: 1.2005x; 1.2005x over previous
//
#include <hip/hip_runtime.h>

// Fused quanvolution + FC + log_softmax via MFMA (gfx950).
// Structure = R3 (q-order K, static param mapping, contiguous B preload),
// + 4-deep x prefetch ring, x loads issued BEFORE the weight gather.
//
// logits[16 imgs][10] = q[16][784] @ w[784][10], mfma_f32_16x16x32_bf16.
// Lane l: i16 = l&15 (image / class), g = l>>4 (k-subgroup).
// A frag k-run = patches j0=kb*8+2g, j0+1: two float4 rows (off, off+28).
// B frag: w[class][k..k+7] contiguous from global (L2-hot), bf16 regs.
// K split over 4 waves (kb = wv + 4I, 25 kblocks), partials via 3KB LDS.
// C frag (m89): col = lane&15, row = (lane>>4)*4 + reg.

typedef __attribute__((ext_vector_type(8))) short short8;
typedef __attribute__((ext_vector_type(4))) float f32x4;

constexpr int WAVES = 4;
constexpr int BLOCK = WAVES * 64;
constexpr int IMGS  = 16;
constexpr int NITER = 7;
constexpr int PF    = 4;    // prefetch depth (ring, statically indexed)

static __device__ __forceinline__ short f2bf(float f) {
    union { float f; unsigned u; } v; v.f = f;
    unsigned r = v.u + 0x7fffu + ((v.u >> 16) & 1u);   // round-to-nearest-even
    return (short)(r >> 16);
}

__global__ __launch_bounds__(BLOCK, 4)
void quanv_mfma(const float* __restrict__ x,
                const float* __restrict__ vqc,
                const float* __restrict__ fc_w,
                const float* __restrict__ fc_b,
                const float* __restrict__ bias,
                float* __restrict__ out,
                int B)
{
    __shared__ float cpart[3][64 * 4];

    const int tid  = threadIdx.x;
    const int lane = tid & 63;
    const int wv   = tid >> 6;
    const int i16  = lane & 15;          // image (A row) / class (B col)
    const int g    = lane >> 4;          // k-subgroup

    const int imgBase = blockIdx.x * IMGS;
    const int imgLane = imgBase + i16;
    const long xb = (long)(imgLane < B ? imgLane : B - 1) * 784;
    const float* __restrict__ xpb = x + xb;

    // x float-offset of patch-pair for iteration I (row-major patch grid)
    auto xoff = [&](int I) -> int {
        const int kb = wv + 4 * I;
        int j0 = kb * 8 + 2 * g;
        if (j0 > 194) j0 = 0;                    // clamp; masked in compute
        const int r = j0 / 14, c = j0 - 14 * r;  // j0 even -> c even -> aligned
        return 56 * r + 2 * c;
    };

    // ---- issue x loads for I=0..3 FIRST: start the HBM stream at cycle 0 ----
    float4 bT[PF], bB[PF];
    #pragma unroll
    for (int I = 0; I < PF; ++I) {
        const int o = xoff(I);
        bT[I] = *reinterpret_cast<const float4*>(xpb + o);        // row 2r
        bB[I] = *reinterpret_cast<const float4*>(xpb + o + 28);   // row 2r+1
    }

    // ---- circuit params (overlap x-load latency) ----
    float S0, C0, S1, C1, S2, C2, S3, C3;
    __sincosf(vqc[0], &S0, &C0);
    __sincosf(vqc[1], &S1, &C1);
    __sincosf(vqc[2], &S2, &C2);
    __sincosf(vqc[3], &S3, &C3);

    // ---- B fragments: contiguous float4 pairs, converted to bf16 ----
    const int ncl = (i16 < 10) ? i16 : 9;        // clamped; garbage cols unread
    const float* __restrict__ wrow = fc_w + ncl * 784;
    short8 bf[NITER];
    #pragma unroll
    for (int I = 0; I < NITER; ++I) {
        const int kb = wv + 4 * I;
        int k = kb * 32 + g * 8;
        if (k > 776) k = 776;                    // in-bounds; A=0 masks tail
        const float4 lo = *reinterpret_cast<const float4*>(wrow + k);
        const float4 hi = *reinterpret_cast<const float4*>(wrow + k + 4);
        short8 t;
        t[0] = f2bf(lo.x); t[1] = f2bf(lo.y); t[2] = f2bf(lo.z); t[3] = f2bf(lo.w);
        t[4] = f2bf(hi.x); t[5] = f2bf(hi.y); t[6] = f2bf(hi.z); t[7] = f2bf(hi.w);
        bf[I] = t;
    }

    f32x4 acc = {0.f, 0.f, 0.f, 0.f};

    #pragma unroll
    for (int I = 0; I < NITER; ++I) {
        const float4 a4 = bT[I & 3];
        const float4 b4 = bB[I & 3];

        if (I + PF < NITER) {                    // maintain 4-deep ring
            const int o = xoff(I + PF);
            bT[I & 3] = *reinterpret_cast<const float4*>(xpb + o);
            bB[I & 3] = *reinterpret_cast<const float4*>(xpb + o + 28);
        }

        const int   j0  = (wv + 4 * I) * 8 + 2 * g;
        const float msk = (j0 <= 194) ? 1.f : 0.f;

        // patch j0: top row (a4.x,a4.y) -> params p0,p1 (STATIC mapping);
        //           bottom row (b4.x,b4.y) -> params p2,p3
        float sa, ca, sb, cb, sc, cc, sd, cd;
        __sincosf(a4.x, &sa, &ca);  __sincosf(a4.y, &sb, &cb);
        __sincosf(b4.x, &sc, &cc);  __sincosf(b4.y, &sd, &cd);
        const float q0 = (C0 * ca + S0 * (sa * sb)) * msk;
        const float q1 = (C1 * (ca * cb) + S1 * sb) * msk;
        const float q2 = (C2 * cc + S2 * (sc * sd)) * msk;
        const float q3 = (C3 * (cc * cd) + S3 * sd) * msk;
        // patch j0+1
        __sincosf(a4.z, &sa, &ca);  __sincosf(a4.w, &sb, &cb);
        __sincosf(b4.z, &sc, &cc);  __sincosf(b4.w, &sd, &cd);
        const float q4 = (C0 * ca + S0 * (sa * sb)) * msk;
        const float q5 = (C1 * (ca * cb) + S1 * sb) * msk;
        const float q6 = (C2 * cc + S2 * (sc * sd)) * msk;
        const float q7 = (C3 * (cc * cd) + S3 * sd) * msk;

        short8 a;
        a[0] = f2bf(q0); a[1] = f2bf(q1); a[2] = f2bf(q2); a[3] = f2bf(q3);
        a[4] = f2bf(q4); a[5] = f2bf(q5); a[6] = f2bf(q6); a[7] = f2bf(q7);

        acc = __builtin_amdgcn_mfma_f32_16x16x32_bf16(a, bf[I], acc, 0, 0, 0);
    }

    // ---- K-split combine through LDS ----
    if (wv > 0)
        *reinterpret_cast<f32x4*>(&cpart[wv - 1][lane * 4]) = acc;
    __syncthreads();

    if (wv == 0) {
        #pragma unroll
        for (int p = 0; p < 3; ++p)
            acc += *reinterpret_cast<const f32x4*>(&cpart[p][lane * 4]);
        const float bk = (i16 < 10) ? (fc_b[i16] - bias[i16]) : 0.f;

        #pragma unroll
        for (int r = 0; r < 4; ++r) {
            const float lg = acc[r] + bk;
            float mx = (i16 < 10) ? lg : -3.0e38f;
            #pragma unroll
            for (int off = 1; off < 16; off <<= 1)
                mx = fmaxf(mx, __shfl_xor(mx, off, 64));
            float s = (i16 < 10) ? __expf(lg - mx) : 0.f;
            #pragma unroll
            for (int off = 1; off < 16; off <<= 1)
                s += __shfl_xor(s, off, 64);
            const int im = imgBase + g * 4 + r;      // C row = g*4 + reg [m89]
            if (i16 < 10 && im < B)
                out[(long)im * 10 + i16] = lg - mx - __logf(s);
        }
    }
}

extern "C" void kernel_launch(void* const* d_in, const int* in_sizes, int n_in,
                              void* d_out, int out_size, void* d_ws, size_t ws_size,
                              hipStream_t stream) {
    const float* x    = (const float*)d_in[0];
    const float* vqc  = (const float*)d_in[1];
    const float* fc_w = (const float*)d_in[2];
    const float* fc_b = (const float*)d_in[3];
    const float* bias = (const float*)d_in[4];
    float* outp = (float*)d_out;

    const int B = in_sizes[0] / 784;
    const int nblocks = (B + IMGS - 1) / IMGS;
    hipLaunchKernelGGL(quanv_mfma, dim3(nblocks), dim3(BLOCK), 0, stream,
                       x, vqc, fc_w, fc_b, bias, outp, B);
}